// Round 3
// baseline (1752.464 us; speedup 1.0000x reference)
//
#include <hip/hip_runtime.h>
#include <hip/hip_bf16.h>
#include <stdint.h>
#include <stddef.h>

typedef short v8s __attribute__((ext_vector_type(8)));
typedef float v4f __attribute__((ext_vector_type(4)));

#define STEPSZ 0.01f

/* workspace layout (bytes). All bf16 operand matrices use the XOR-swizzled
 * layout: row pitch = K*2B; the 16B chunk at position p of row r holds
 * logical k-chunk (p ^ (r&7)). DMA stages positions linearly; fragment
 * readers de-swizzle -> conflict-free ds_read_b128. */
#define OFF_ARE 0u        /* bf16 [2048][512]  2 MB : B^T fwd  (rows (m,j)) */
#define OFF_ATT 2097152u  /* bf16 [4096][256]  2 MB : B^T bwd  (rows (n,j)) */
#define OFF_XB  4194304u  /* bf16 [512][512] 512 KB : x operand (rows (b,i)) */
#define OFF_ERR 4718592u  /* bf16 [512][256] 256 KB : err operand (rows (b,i)) */
#define OFF_YT  4980736u  /* f32  [512][256] 512 KB : y transposed (rows (b,k)) */
#define OFF_BAR 5505024u  /* int  [256]            : cluster barriers */

__device__ __forceinline__ void async_lds16(const void* g, void* l) {
  __builtin_amdgcn_global_load_lds(
      (const __attribute__((address_space(1))) uint32_t*)g,
      (__attribute__((address_space(3))) uint32_t*)l, 16, 0, 0);
}

/* AreT row R=m*8+j holds A[m,n,j] over n (swizzled) */
__global__ void prep_fwd(const float* __restrict__ A, __hip_bfloat16* __restrict__ AreT) {
  const int m = blockIdx.x;   // 256
  const int n = threadIdx.x;  // 512
  const float* ap = A + ((size_t)m * 512 + n) * 8;
#pragma unroll
  for (int j = 0; j < 8; ++j) {
    const int R = m * 8 + j;
    AreT[(size_t)R * 512 + (((n >> 3) ^ (R & 7)) << 3) + (n & 7)] = __float2bfloat16(ap[j]);
  }
}

/* AtT row R=n*8+j holds A[m,n,j]*rev[j] over m (swizzled) */
__global__ void prep_bwd(const float* __restrict__ A, __hip_bfloat16* __restrict__ AtT) {
  const int n = blockIdx.x;   // 512
  const int m = threadIdx.x;  // 256
  const float* ap = A + ((size_t)m * 512 + n) * 8;
  const float rev[8] = {1.f, 1.f, 1.f, -1.f, 1.f, -1.f, -1.f, -1.f};
#pragma unroll
  for (int j = 0; j < 8; ++j) {
    const int R = n * 8 + j;
    AtT[(size_t)R * 256 + (((m >> 3) ^ (R & 7)) << 3) + (m & 7)] = __float2bfloat16(ap[j] * rev[j]);
  }
}

/* yT[(b*8+k)*256 + m] = y[(b*256+m)*8 + k] */
__global__ void prep_y(const float* __restrict__ y, float* __restrict__ yT) {
  const int r = blockIdx.x;   // 512
  const int m = threadIdx.x;  // 256
  yT[(size_t)r * 256 + m] = y[((size_t)(r >> 3) * 256 + m) * 8 + (r & 7)];
}

__global__ void zero_x(__hip_bfloat16* __restrict__ xb, int* __restrict__ bar) {
  const int idx = blockIdx.x * blockDim.x + threadIdx.x;  // 262144
  xb[idx] = __float2bfloat16(0.f);
  if (idx < 256) bar[idx] = 0;
}

/* monotonic intra-cluster barrier (32 blocks, one XCD under %8 swizzle) */
__device__ __forceinline__ void cbar(int* bar, int target) {
  __syncthreads();
  if (threadIdx.x == 0) {
    __threadfence();
    atomicAdd(bar, 1);
    while (__hip_atomic_load(bar, __ATOMIC_RELAXED, __HIP_MEMORY_SCOPE_AGENT) < target)
      __builtin_amdgcn_s_sleep(1);
    __threadfence();
  }
  __syncthreads();
}

/* Persistent kernel: 256 blocks x 512 threads. Cluster = blockIdx&7 (one XCD),
 * 32 members (w = blockIdx>>3). Cluster owns batches [cl*8, cl*8+8) = 64 rows.
 * Member w owns 64 fwd cols (m,j) and 128 bwd cols (n,j). x fp32 master lives
 * in registers (owner-computes). 2 intra-XCD barriers per iteration. */
__global__ __launch_bounds__(512) void ista_persist(
    const __hip_bfloat16* __restrict__ AreT, const __hip_bfloat16* __restrict__ AtT,
    const float* __restrict__ yT, __hip_bfloat16* __restrict__ errb,
    __hip_bfloat16* __restrict__ xb, float* __restrict__ out, int* __restrict__ bars) {
  /* arena: [0,16K) A-operand dbuf (8K each) | [16K,48K) B dbuf
   * (ph1: 8K bufs @16K/@24K; ph2: 16K bufs @16K/@32K) | [48K, +8448) Pt */
  __shared__ __align__(16) char arena[57600];
  float* const Pt = (float*)(arena + 49152);

  const int tid = threadIdx.x;
  const int wave = tid >> 6, lane = tid & 63;
  const int fr = lane & 15, fq = lane >> 4;
  const int band = wave >> 1, cg = wave & 1;  // 4 row-bands x 2 col-groups
  const int cl = blockIdx.x & 7, w = blockIdx.x >> 3;
  const int rowbase = cl * 64;
  int* bar = bars + cl * 32;
  int ep = 0;

  const char* const gxb = (const char*)xb;
  const char* const gerr = (const char*)errb;
  const char* const gB1 = (const char*)(AreT + (size_t)(w * 64) * 512);
  const char* const gB2 = (const char*)(AtT + (size_t)(w * 128) * 256);

  float xreg[4] = {0.f, 0.f, 0.f, 0.f};

  /* chunk = 64 k = 128 B per row. LDS row pitch 128 B, slot = kq ^ (r&7). */
  auto frag = [&](const char* buf, int row, int kq) -> v8s {
    return *(const v8s*)(buf + row * 128 + ((kq ^ (row & 7)) << 4));
  };
  auto dmaA1 = [&](int ch) {  // x rows, pitch 1024 B
    async_lds16(gxb + (size_t)(rowbase + (tid >> 3)) * 1024 + ch * 128 + (tid & 7) * 16,
                arena + (ch & 1) * 8192 + wave * 1024);
  };
  auto dmaB1 = [&](int ch) {  // AreT member rows, pitch 1024 B
    async_lds16(gB1 + (size_t)(tid >> 3) * 1024 + ch * 128 + (tid & 7) * 16,
                arena + 16384 + (ch & 1) * 8192 + wave * 1024);
  };
  auto dmaA2 = [&](int ch) {  // err rows, pitch 512 B
    async_lds16(gerr + (size_t)(rowbase + (tid >> 3)) * 512 + ch * 128 + (tid & 7) * 16,
                arena + (ch & 1) * 8192 + wave * 1024);
  };
  auto dmaB2 = [&](int ch) {  // AtT member rows (128), pitch 512 B
#pragma unroll
    for (int g = 0; g < 2; ++g)
      async_lds16(gB2 + (size_t)(g * 64 + (tid >> 3)) * 512 + ch * 128 + (tid & 7) * 16,
                  arena + 16384 + (ch & 1) * 16384 + g * 8192 + wave * 1024);
  };

  dmaB1(0);  // prefetch iter-0 phase-1 B

  for (int it = 0; it < 50; ++it) {
    /* ================= PHASE 1: err = recomb(x @ AreT^T) - y ================ */
    {
      dmaA1(0);
      v4f acc0 = {}, acc1 = {};
      for (int ch = 0; ch < 8; ++ch) {
        __syncthreads();
        if (ch < 7) { dmaA1(ch + 1); dmaB1(ch + 1); }
        const char* bA = arena + (ch & 1) * 8192;
        const char* bB = arena + 16384 + (ch & 1) * 8192;
#pragma unroll
        for (int s = 0; s < 2; ++s) {
          const int kq = s * 4 + fq;
          v8s a = frag(bA, band * 16 + fr, kq);
          v8s b0 = frag(bB, cg * 32 + fr, kq);
          v8s b1 = frag(bB, cg * 32 + 16 + fr, kq);
          acc0 = __builtin_amdgcn_mfma_f32_16x16x32_bf16(a, b0, acc0, 0, 0, 0);
          acc1 = __builtin_amdgcn_mfma_f32_16x16x32_bf16(a, b1, acc1, 0, 0, 0);
        }
      }
      for (int cc = 0; cc < 2; ++cc) {
        __syncthreads();
        if (cc == 0) dmaB2(0);  // prefetch phase-2 B (regions now dead)
        if (cg == cc) {
#pragma unroll
          for (int v = 0; v < 4; ++v) {
            Pt[(band * 16 + fq * 4 + v) * 33 + fr] = acc0[v];
            Pt[(band * 16 + fq * 4 + v) * 33 + 16 + fr] = acc1[v];
          }
        }
        __syncthreads();
        if (tid < 256) {
          const int ro = tid >> 2, ml = tid & 3;
          const int k = ro & 7, bl = ro >> 3;
          float s = 0.f;
#pragma unroll
          for (int j = 0; j < 8; ++j) {
            const int i = k ^ j;
            const int cnt = __popc((i >> 1) & j) + __popc((i >> 2) & j);
            const float p = Pt[(bl * 8 + i) * 33 + ml * 8 + j];
            s += (cnt & 1) ? -p : p;
          }
          const int row = rowbase + ro;
          const int m = w * 8 + cc * 4 + ml;
          const float e = s - yT[(size_t)row * 256 + m];
          errb[(size_t)row * 256 + ((w ^ (row & 7)) << 3) + (m & 7)] = __float2bfloat16(e);
        }
      }
      cbar(bar, ++ep * 32);
    }
    /* ============ PHASE 2: grad = recomb(err @ AtT^T); x update ============ */
    {
      dmaA2(0);  // B2 chunk 0 already prefetched
      v4f acc[4] = {};
      for (int ch = 0; ch < 4; ++ch) {
        __syncthreads();
        if (ch < 3) { dmaA2(ch + 1); dmaB2(ch + 1); }
        const char* bA = arena + (ch & 1) * 8192;
        const char* bB = arena + 16384 + (ch & 1) * 16384;
#pragma unroll
        for (int s = 0; s < 2; ++s) {
          const int kq = s * 4 + fq;
          v8s a = frag(bA, band * 16 + fr, kq);
#pragma unroll
          for (int ct = 0; ct < 4; ++ct) {
            v8s b = frag(bB, cg * 64 + ct * 16 + fr, kq);
            acc[ct] = __builtin_amdgcn_mfma_f32_16x16x32_bf16(a, b, acc[ct], 0, 0, 0);
          }
        }
      }
      if (it < 49) dmaB1(0);  // prefetch next-iter phase-1 B (disjoint region)
      for (int cc = 0; cc < 4; ++cc) {
        __syncthreads();
        if (cg == (cc >> 1)) {
          const int c0 = (cc & 1) * 2;
#pragma unroll
          for (int t2 = 0; t2 < 2; ++t2)
#pragma unroll
            for (int v = 0; v < 4; ++v)
              Pt[(band * 16 + fq * 4 + v) * 33 + t2 * 16 + fr] = acc[c0 + t2][v];
        }
        __syncthreads();
        if (tid < 256) {
          const int ro = tid >> 2, nl = tid & 3;
          const int k = ro & 7, bl = ro >> 3;
          float s = 0.f;
#pragma unroll
          for (int j = 0; j < 8; ++j) {
            const int i = k ^ j;
            const int cnt = __popc((i >> 1) & j) + __popc((i >> 2) & j);
            const float p = Pt[(bl * 8 + i) * 33 + nl * 8 + j];
            s += (cnt & 1) ? -p : p;
          }
          float xv = xreg[cc] - STEPSZ * s;
          const float thr = (k == 0) ? 0.f : ((k == 7) ? 0.002f : 0.001f);
          const float ax = fabsf(xv) - thr;
          xv = (ax > 0.f) ? copysignf(ax, xv) : 0.f;
          xreg[cc] = xv;
          const int row = rowbase + ro;
          const int n = w * 16 + cc * 4 + nl;
          xb[(size_t)row * 512 + (((n >> 3) ^ (row & 7)) << 3) + (n & 7)] = __float2bfloat16(xv);
          if (it == 49) out[((size_t)(cl * 8 + bl) * 512 + n) * 8 + k] = xv;
        }
      }
      if (it < 49) cbar(bar, ++ep * 32);
    }
  }
}

extern "C" void kernel_launch(void* const* d_in, const int* in_sizes, int n_in,
                              void* d_out, int out_size, void* d_ws, size_t ws_size,
                              hipStream_t stream) {
  (void)in_sizes; (void)n_in; (void)out_size; (void)ws_size;
  const float* y = (const float*)d_in[0];
  const float* A = (const float*)d_in[1];
  float* out = (float*)d_out;
  char* ws = (char*)d_ws;

  __hip_bfloat16* AreT = (__hip_bfloat16*)(ws + OFF_ARE);
  __hip_bfloat16* AtT = (__hip_bfloat16*)(ws + OFF_ATT);
  __hip_bfloat16* xb = (__hip_bfloat16*)(ws + OFF_XB);
  __hip_bfloat16* errb = (__hip_bfloat16*)(ws + OFF_ERR);
  float* yT = (float*)(ws + OFF_YT);
  int* bars = (int*)(ws + OFF_BAR);

  prep_fwd<<<256, 512, 0, stream>>>(A, AreT);
  prep_bwd<<<512, 256, 0, stream>>>(A, AtT);
  prep_y<<<512, 256, 0, stream>>>(y, yT);
  zero_x<<<1024, 256, 0, stream>>>(xb, bars);

  ista_persist<<<256, 512, 0, stream>>>(AreT, AtT, yT, errb, xb, out, bars);
}

// Round 4
// 1731.567 us; speedup vs baseline: 1.0121x; 1.0121x over previous
//
#include <hip/hip_runtime.h>
#include <hip/hip_bf16.h>
#include <stdint.h>
#include <stddef.h>

typedef short v8s __attribute__((ext_vector_type(8)));
typedef float v4f __attribute__((ext_vector_type(4)));

#define STEPSZ 0.01f
#define MFMA(a, b, c) __builtin_amdgcn_mfma_f32_16x16x32_bf16((a), (b), (c), 0, 0, 0)

/* workspace layout (bytes) — all PLAIN row-major layouts */
#define OFF_ARE 0u        /* bf16 [2048][512] 2 MB : AreT rows (m*8+j) over n */
#define OFF_ATT 2097152u  /* bf16 [4096][256] 2 MB : AtT rows (n*8+j) over m (rev folded) */
#define OFF_XB  4194304u  /* bf16 [512][512] 512 KB : x operand rows (b*8+i) */
#define OFF_ERR 4718592u  /* bf16 [512][256] 256 KB : err operand rows (b*8+i) */
#define OFF_YT  4980736u  /* f32  [512][256] 512 KB : y transposed rows (b*8+k) */
#define OFF_BAR 5505024u  /* int  [256]             : cluster barriers */

__global__ void prep_fwd(const float* __restrict__ A, __hip_bfloat16* __restrict__ AreT) {
  const int m = blockIdx.x;   // 256
  const int n = threadIdx.x;  // 512
  const float* ap = A + ((size_t)m * 512 + n) * 8;
#pragma unroll
  for (int j = 0; j < 8; ++j)
    AreT[(size_t)(m * 8 + j) * 512 + n] = __float2bfloat16(ap[j]);
}

__global__ void prep_bwd(const float* __restrict__ A, __hip_bfloat16* __restrict__ AtT) {
  const int n = blockIdx.x;   // 512
  const int m = threadIdx.x;  // 256
  const float* ap = A + ((size_t)m * 512 + n) * 8;
  const float rev[8] = {1.f, 1.f, 1.f, -1.f, 1.f, -1.f, -1.f, -1.f};
#pragma unroll
  for (int j = 0; j < 8; ++j)
    AtT[(size_t)(n * 8 + j) * 256 + m] = __float2bfloat16(ap[j] * rev[j]);
}

__global__ void prep_y(const float* __restrict__ y, float* __restrict__ yT) {
  const int r = blockIdx.x;   // 512
  const int m = threadIdx.x;  // 256
  yT[(size_t)r * 256 + m] = y[((size_t)(r >> 3) * 256 + m) * 8 + (r & 7)];
}

__global__ void zero_x(__hip_bfloat16* __restrict__ xb, int* __restrict__ bar) {
  const int idx = blockIdx.x * blockDim.x + threadIdx.x;  // 262144
  xb[idx] = __float2bfloat16(0.f);
  if (idx < 256) bar[idx] = 0;
}

/* monotonic intra-cluster barrier (32 blocks); fence gives cross-block data
 * visibility (and L1/L2 inv that protects the subsequent plain loads). */
__device__ __forceinline__ void cbar(int* bar, int target) {
  __syncthreads();
  if (threadIdx.x == 0) {
    __threadfence();
    atomicAdd(bar, 1);
    while (__hip_atomic_load(bar, __ATOMIC_RELAXED, __HIP_MEMORY_SCOPE_AGENT) < target)
      __builtin_amdgcn_s_sleep(1);
    __threadfence();
  }
  __syncthreads();
}

/* Persistent kernel: 256 blocks x 512 thr, 1 block/CU (148 KB LDS).
 * Cluster = blockIdx&7 (one XCD, 32 members), member w = blockIdx>>3.
 * Cluster owns batches [cl*8,cl*8+8) = 64 GEMM rows (b,i).
 * Block w owns fwd cols m in [w*8,w*8+8), bwd cols n in [w*16,w*16+16).
 * B operands persist in LDS for all 50 iterations (immune to fence
 * invalidation). K-loops are barrier-free per-wave. */
__global__ __launch_bounds__(512) void ista_persist(
    const __hip_bfloat16* __restrict__ AreT, const __hip_bfloat16* __restrict__ AtT,
    const float* __restrict__ yT, __hip_bfloat16* __restrict__ errb,
    __hip_bfloat16* __restrict__ xb, float* __restrict__ out, int* __restrict__ bars) {
  /* [0,64K) B1[64][512] bf16 | [64K,128K) B2[128][256] bf16 | [128K,+16896) Pt f32[64][66]
   * B LDS: 16B chunk c of row r stored at chunk (c ^ (r&7)) -> 2-way max on frag reads */
  __shared__ __align__(16) char lds[147968];
  float* const Pt = (float*)(lds + 131072);

  const int tid = threadIdx.x;
  const int wave = tid >> 6, lane = tid & 63;
  const int fr = lane & 15, fq = lane >> 4;
  const int band = wave >> 1, cg = wave & 1;  // 4 row-bands x 2 col-groups
  const int cl = blockIdx.x & 7, w = blockIdx.x >> 3;
  const int rowbase = cl * 64;
  int* bar = bars + cl * 32;
  int ep = 0;

  /* ---- prologue: load this block's B slices into persistent LDS (once) ---- */
  {
    const __hip_bfloat16* gB1 = AreT + (size_t)(w * 64) * 512;
    const __hip_bfloat16* gB2 = AtT + (size_t)(w * 128) * 256;
#pragma unroll
    for (int rr = 0; rr < 8; ++rr) {
      const int r = tid >> 3, c = (tid & 7) + rr * 8;          // 64 rows x 64 chunks
      v8s v = *(const v8s*)(gB1 + (size_t)r * 512 + c * 8);
      *(v8s*)(lds + r * 1024 + ((c ^ (r & 7)) << 4)) = v;
    }
#pragma unroll
    for (int rr = 0; rr < 8; ++rr) {
      const int r = tid >> 2, c = (tid & 3) + rr * 4;          // 128 rows x 32 chunks
      v8s v = *(const v8s*)(gB2 + (size_t)r * 256 + c * 8);
      *(v8s*)(lds + 65536 + r * 512 + ((c ^ (r & 7)) << 4)) = v;
    }
    __syncthreads();
  }

  float xreg[2] = {0.f, 0.f};
  const int ro = tid >> 3;          // epilogue output row 0..63
  const int bl = ro >> 3, k = ro & 7;
  const float thr = (k == 0) ? 0.f : ((k == 7) ? 0.002f : 0.001f);

  for (int it = 0; it < 50; ++it) {
    /* ================= PHASE 1: err = recomb(x @ B1^T) - y ================ */
    if (it == 0) {
      /* x0 = 0 -> err = -y */
      const int ml = tid & 7;
      const size_t eidx = (size_t)(rowbase + ro) * 256 + w * 8 + ml;
      errb[eidx] = __float2bfloat16(-yT[eidx]);
      cbar(bar, ++ep * 32);
    } else {
      v4f acc0 = {}, acc1 = {};
      const __hip_bfloat16* aRow = xb + (size_t)(rowbase + band * 16 + fr) * 512;
      const int rB0 = cg * 32 + fr, rB1 = cg * 32 + 16 + fr;
#pragma unroll
      for (int kq = 0; kq < 16; ++kq) {
        v8s a = *(const v8s*)(aRow + kq * 32 + fq * 8);
        const int c = kq * 4 + fq;
        v8s b0 = *(const v8s*)(lds + rB0 * 1024 + ((c ^ (rB0 & 7)) << 4));
        v8s b1 = *(const v8s*)(lds + rB1 * 1024 + ((c ^ (rB1 & 7)) << 4));
        acc0 = MFMA(a, b0, acc0);
        acc1 = MFMA(a, b1, acc1);
      }
      /* epilogue: dump P (64x64), recombine blades, write err slice */
#pragma unroll
      for (int v = 0; v < 4; ++v) {
        Pt[(band * 16 + fq * 4 + v) * 66 + cg * 32 + fr] = acc0[v];
        Pt[(band * 16 + fq * 4 + v) * 66 + cg * 32 + 16 + fr] = acc1[v];
      }
      __syncthreads();
      {
        const int ml = tid & 7;
        float s = 0.f;
#pragma unroll
        for (int j = 0; j < 8; ++j) {
          const int i = k ^ j;
          const int cnt = __popc((i >> 1) & j) + __popc((i >> 2) & j);
          const float p = Pt[(bl * 8 + i) * 66 + ml * 8 + j];
          s += (cnt & 1) ? -p : p;
        }
        const size_t eidx = (size_t)(rowbase + ro) * 256 + w * 8 + ml;
        errb[eidx] = __float2bfloat16(s - yT[eidx]);
      }
      cbar(bar, ++ep * 32);
    }
    /* ============ PHASE 2: grad = recomb(err @ B2^T); x update ============ */
    {
      v4f acc[4] = {};
      const __hip_bfloat16* eRow = errb + (size_t)(rowbase + band * 16 + fr) * 256;
#pragma unroll
      for (int kq = 0; kq < 8; ++kq) {
        v8s a = *(const v8s*)(eRow + kq * 32 + fq * 8);
        const int c = kq * 4 + fq;
#pragma unroll
        for (int ct = 0; ct < 4; ++ct) {
          const int rB = cg * 64 + ct * 16 + fr;
          v8s b = *(const v8s*)(lds + 65536 + rB * 512 + ((c ^ (rB & 7)) << 4));
          acc[ct] = MFMA(a, b, acc[ct]);
        }
      }
      /* epilogue in 2 column-halves of 64 (Pt reused) */
#pragma unroll
      for (int h = 0; h < 2; ++h) {
        __syncthreads();
        if (cg == h) {
#pragma unroll
          for (int ct = 0; ct < 4; ++ct)
#pragma unroll
            for (int v = 0; v < 4; ++v)
              Pt[(band * 16 + fq * 4 + v) * 66 + ct * 16 + fr] = acc[ct][v];
        }
        __syncthreads();
        {
          const int nl = tid & 7;
          float s = 0.f;
#pragma unroll
          for (int j = 0; j < 8; ++j) {
            const int i = k ^ j;
            const int cnt = __popc((i >> 1) & j) + __popc((i >> 2) & j);
            const float p = Pt[(bl * 8 + i) * 66 + nl * 8 + j];
            s += (cnt & 1) ? -p : p;
          }
          float xv = xreg[h] - STEPSZ * s;
          const float ax = fabsf(xv) - thr;
          xv = (ax > 0.f) ? copysignf(ax, xv) : 0.f;
          xreg[h] = xv;
          const int n = w * 16 + h * 8 + nl;
          xb[(size_t)(rowbase + ro) * 512 + n] = __float2bfloat16(xv);
          if (it == 49) out[((size_t)(cl * 8 + bl) * 512 + n) * 8 + k] = xv;
        }
      }
      if (it < 49) cbar(bar, ++ep * 32);
    }
  }
}

extern "C" void kernel_launch(void* const* d_in, const int* in_sizes, int n_in,
                              void* d_out, int out_size, void* d_ws, size_t ws_size,
                              hipStream_t stream) {
  (void)in_sizes; (void)n_in; (void)out_size; (void)ws_size;
  const float* y = (const float*)d_in[0];
  const float* A = (const float*)d_in[1];
  float* out = (float*)d_out;
  char* ws = (char*)d_ws;

  __hip_bfloat16* AreT = (__hip_bfloat16*)(ws + OFF_ARE);
  __hip_bfloat16* AtT = (__hip_bfloat16*)(ws + OFF_ATT);
  __hip_bfloat16* xb = (__hip_bfloat16*)(ws + OFF_XB);
  __hip_bfloat16* errb = (__hip_bfloat16*)(ws + OFF_ERR);
  float* yT = (float*)(ws + OFF_YT);
  int* bars = (int*)(ws + OFF_BAR);

  prep_fwd<<<256, 512, 0, stream>>>(A, AreT);
  prep_bwd<<<512, 256, 0, stream>>>(A, AtT);
  prep_y<<<512, 256, 0, stream>>>(y, yT);
  zero_x<<<1024, 256, 0, stream>>>(xb, bars);

  ista_persist<<<256, 512, 0, stream>>>(AreT, AtT, yT, errb, xb, out, bars);
}

// Round 5
// 754.181 us; speedup vs baseline: 2.3237x; 2.2960x over previous
//
#include <hip/hip_runtime.h>
#include <hip/hip_bf16.h>
#include <stdint.h>
#include <stddef.h>

typedef short v8s __attribute__((ext_vector_type(8)));
typedef short v4s __attribute__((ext_vector_type(4)));
typedef float v4f __attribute__((ext_vector_type(4)));

#define STEPSZ 0.01f
#define MFMA(a, b, c) __builtin_amdgcn_mfma_f32_16x16x32_bf16((a), (b), (c), 0, 0, 0)

/* workspace layout (bytes) — all PLAIN row-major layouts */
#define OFF_ARE 0u        /* bf16 [2048][512] 2 MB : AreT rows (m*8+j) over n */
#define OFF_ATT 2097152u  /* bf16 [4096][256] 2 MB : AtT rows (n*8+j) over m (rev folded) */
#define OFF_XB  4194304u  /* bf16 [512][512] 512 KB : x operand rows (b*8+i) */
#define OFF_ERR 4718592u  /* bf16 [512][256] 256 KB : err operand rows (b*8+i) */
#define OFF_YT  4980736u  /* f32  [512][256] 512 KB : y transposed rows (b*8+k) */
#define OFF_BAR 5505024u  /* int  [256]             : per-block barrier flag slots */

/* ---- agent-scope (coherence-point) data path: no fences, no wbl2, ever ---- */
__device__ __forceinline__ v8s aload16(const void* p) {
  typedef unsigned long long u64;
  u64 lo = __hip_atomic_load((const u64*)p, __ATOMIC_RELAXED, __HIP_MEMORY_SCOPE_AGENT);
  u64 hi = __hip_atomic_load((const u64*)p + 1, __ATOMIC_RELAXED, __HIP_MEMORY_SCOPE_AGENT);
  union { u64 u; v4s s; } a, b;
  a.u = lo; b.u = hi;
  return __builtin_shufflevector(a.s, b.s, 0, 1, 2, 3, 4, 5, 6, 7);
}
__device__ __forceinline__ void astore_bf16(__hip_bfloat16* p, float v) {
  __hip_bfloat16 h = __float2bfloat16(v);
  unsigned short bits;
  __builtin_memcpy(&bits, &h, 2);
  __hip_atomic_store((unsigned short*)p, bits, __ATOMIC_RELAXED, __HIP_MEMORY_SCOPE_AGENT);
}

__global__ void prep_fwd(const float* __restrict__ A, __hip_bfloat16* __restrict__ AreT) {
  const int m = blockIdx.x;   // 256
  const int n = threadIdx.x;  // 512
  const float* ap = A + ((size_t)m * 512 + n) * 8;
#pragma unroll
  for (int j = 0; j < 8; ++j)
    AreT[(size_t)(m * 8 + j) * 512 + n] = __float2bfloat16(ap[j]);
}

__global__ void prep_bwd(const float* __restrict__ A, __hip_bfloat16* __restrict__ AtT) {
  const int n = blockIdx.x;   // 512
  const int m = threadIdx.x;  // 256
  const float* ap = A + ((size_t)m * 512 + n) * 8;
  const float rev[8] = {1.f, 1.f, 1.f, -1.f, 1.f, -1.f, -1.f, -1.f};
#pragma unroll
  for (int j = 0; j < 8; ++j)
    AtT[(size_t)(n * 8 + j) * 256 + m] = __float2bfloat16(ap[j] * rev[j]);
}

__global__ void prep_y(const float* __restrict__ y, float* __restrict__ yT) {
  const int r = blockIdx.x;   // 512
  const int m = threadIdx.x;  // 256
  yT[(size_t)r * 256 + m] = y[((size_t)(r >> 3) * 256 + m) * 8 + (r & 7)];
}

__global__ void zero_flags(int* __restrict__ bar) {
  __hip_atomic_store(bar + threadIdx.x, 0, __ATOMIC_RELAXED, __HIP_MEMORY_SCOPE_AGENT);
}

/* Flag-array cluster barrier: per-block slots (no RMW contention), release via
 * syncthreads' vmcnt(0) drain (all data stores are write-through agent-scope,
 * so drained == globally visible). No cache-maintenance instructions. */
__device__ __forceinline__ void flagbar(int* flags, int w, int ep) {
  __syncthreads();  // drains vmcnt per wave -> all agent stores at L3
  const int tid = threadIdx.x;
  if (tid == 0)
    __hip_atomic_store(flags + w, ep, __ATOMIC_RELAXED, __HIP_MEMORY_SCOPE_AGENT);
  if (tid < 64) {
    const int s = tid & 31;
    while (__hip_atomic_load(flags + s, __ATOMIC_RELAXED, __HIP_MEMORY_SCOPE_AGENT) < ep)
      __builtin_amdgcn_s_sleep(1);
  }
  __syncthreads();
  asm volatile("" ::: "memory");  // compiler fence: keep data loads after poll
}

/* Persistent kernel: 256 blocks x 512 thr, 1 block/CU (148 KB LDS).
 * Cluster = blockIdx&7 (32 members, w = blockIdx>>3); owns batches
 * [cl*8,cl*8+8) = 64 GEMM rows (b,i). Block w owns fwd cols m in [w*8,w*8+8),
 * bwd cols n in [w*16,w*16+16). B operands persist in LDS for all 50
 * iterations. All cross-block data via agent-scope atomics (L3 coherence
 * point) -> correct under any block->XCD mapping, zero fences. */
__global__ __launch_bounds__(512) void ista_persist(
    const __hip_bfloat16* __restrict__ AreT, const __hip_bfloat16* __restrict__ AtT,
    const float* __restrict__ yT, __hip_bfloat16* __restrict__ errb,
    __hip_bfloat16* __restrict__ xb, float* __restrict__ out, int* __restrict__ bars) {
  /* [0,64K) B1[64][512] bf16 | [64K,128K) B2[128][256] bf16 | [128K,+16896) Pt f32[64][66]
   * B LDS: 16B chunk c of row r stored at chunk (c ^ (r&7)) -> <=2-way on frag reads */
  __shared__ __align__(16) char lds[147968];
  float* const Pt = (float*)(lds + 131072);

  const int tid = threadIdx.x;
  const int wave = tid >> 6, lane = tid & 63;
  const int fr = lane & 15, fq = lane >> 4;
  const int band = wave >> 1, cg = wave & 1;  // 4 row-bands x 2 col-groups
  const int cl = blockIdx.x & 7, w = blockIdx.x >> 3;
  const int rowbase = cl * 64;
  int* flags = bars + cl * 32;
  int ep = 0;

  /* ---- prologue: load this block's B slices into persistent LDS (once) ---- */
  {
    const __hip_bfloat16* gB1 = AreT + (size_t)(w * 64) * 512;
    const __hip_bfloat16* gB2 = AtT + (size_t)(w * 128) * 256;
#pragma unroll
    for (int rr = 0; rr < 8; ++rr) {
      const int r = tid >> 3, c = (tid & 7) + rr * 8;          // 64 rows x 64 chunks
      v8s v = *(const v8s*)(gB1 + (size_t)r * 512 + c * 8);
      *(v8s*)(lds + r * 1024 + ((c ^ (r & 7)) << 4)) = v;
    }
#pragma unroll
    for (int rr = 0; rr < 8; ++rr) {
      const int r = tid >> 2, c = (tid & 3) + rr * 4;          // 128 rows x 32 chunks
      v8s v = *(const v8s*)(gB2 + (size_t)r * 256 + c * 8);
      *(v8s*)(lds + 65536 + r * 512 + ((c ^ (r & 7)) << 4)) = v;
    }
    __syncthreads();
  }

  float xreg[2] = {0.f, 0.f};
  const int ro = tid >> 3;          // epilogue output row 0..63
  const int bl = ro >> 3, k = ro & 7;
  const float thr = (k == 0) ? 0.f : ((k == 7) ? 0.002f : 0.001f);

  for (int it = 0; it < 50; ++it) {
    /* ================= PHASE 1: err = recomb(x @ B1^T) - y ================ */
    if (it == 0) {
      /* x0 = 0 -> err = -y */
      const int ml = tid & 7;
      const size_t eidx = (size_t)(rowbase + ro) * 256 + w * 8 + ml;
      astore_bf16(errb + eidx, -yT[eidx]);
      flagbar(flags, w, ++ep);
    } else {
      v4f acc0 = {}, acc1 = {};
      const __hip_bfloat16* aRow = xb + (size_t)(rowbase + band * 16 + fr) * 512;
      const int rB0 = cg * 32 + fr, rB1 = cg * 32 + 16 + fr;
#pragma unroll
      for (int kq = 0; kq < 16; ++kq) {
        v8s a = aload16(aRow + kq * 32 + fq * 8);
        const int c = kq * 4 + fq;
        v8s b0 = *(const v8s*)(lds + rB0 * 1024 + ((c ^ (rB0 & 7)) << 4));
        v8s b1 = *(const v8s*)(lds + rB1 * 1024 + ((c ^ (rB1 & 7)) << 4));
        acc0 = MFMA(a, b0, acc0);
        acc1 = MFMA(a, b1, acc1);
      }
      /* epilogue: dump P (64x64), recombine blades, write err slice */
#pragma unroll
      for (int v = 0; v < 4; ++v) {
        Pt[(band * 16 + fq * 4 + v) * 66 + cg * 32 + fr] = acc0[v];
        Pt[(band * 16 + fq * 4 + v) * 66 + cg * 32 + 16 + fr] = acc1[v];
      }
      __syncthreads();
      {
        const int ml = tid & 7;
        float s = 0.f;
#pragma unroll
        for (int j = 0; j < 8; ++j) {
          const int i = k ^ j;
          const int cnt = __popc((i >> 1) & j) + __popc((i >> 2) & j);
          const float p = Pt[(bl * 8 + i) * 66 + ml * 8 + j];
          s += (cnt & 1) ? -p : p;
        }
        const size_t eidx = (size_t)(rowbase + ro) * 256 + w * 8 + ml;
        astore_bf16(errb + eidx, s - yT[eidx]);
      }
      flagbar(flags, w, ++ep);
    }
    /* ============ PHASE 2: grad = recomb(err @ B2^T); x update ============ */
    {
      v4f acc[4] = {};
      const __hip_bfloat16* eRow = errb + (size_t)(rowbase + band * 16 + fr) * 256;
#pragma unroll
      for (int kq = 0; kq < 8; ++kq) {
        v8s a = aload16(eRow + kq * 32 + fq * 8);
        const int c = kq * 4 + fq;
#pragma unroll
        for (int ct = 0; ct < 4; ++ct) {
          const int rB = cg * 64 + ct * 16 + fr;
          v8s b = *(const v8s*)(lds + 65536 + rB * 512 + ((c ^ (rB & 7)) << 4));
          acc[ct] = MFMA(a, b, acc[ct]);
        }
      }
      /* epilogue in 2 column-halves of 64 (Pt reused) */
#pragma unroll
      for (int h = 0; h < 2; ++h) {
        __syncthreads();
        if (cg == h) {
#pragma unroll
          for (int ct = 0; ct < 4; ++ct)
#pragma unroll
            for (int v = 0; v < 4; ++v)
              Pt[(band * 16 + fq * 4 + v) * 66 + ct * 16 + fr] = acc[ct][v];
        }
        __syncthreads();
        {
          const int nl = tid & 7;
          float s = 0.f;
#pragma unroll
          for (int j = 0; j < 8; ++j) {
            const int i = k ^ j;
            const int cnt = __popc((i >> 1) & j) + __popc((i >> 2) & j);
            const float p = Pt[(bl * 8 + i) * 66 + nl * 8 + j];
            s += (cnt & 1) ? -p : p;
          }
          float xv = xreg[h] - STEPSZ * s;
          const float ax = fabsf(xv) - thr;
          xv = (ax > 0.f) ? copysignf(ax, xv) : 0.f;
          xreg[h] = xv;
          const int n = w * 16 + h * 8 + nl;
          astore_bf16(xb + (size_t)(rowbase + ro) * 512 + n, xv);
          if (it == 49) out[((size_t)(cl * 8 + bl) * 512 + n) * 8 + k] = xv;
        }
      }
      if (it < 49) flagbar(flags, w, ++ep);
    }
  }
}

extern "C" void kernel_launch(void* const* d_in, const int* in_sizes, int n_in,
                              void* d_out, int out_size, void* d_ws, size_t ws_size,
                              hipStream_t stream) {
  (void)in_sizes; (void)n_in; (void)out_size; (void)ws_size;
  const float* y = (const float*)d_in[0];
  const float* A = (const float*)d_in[1];
  float* out = (float*)d_out;
  char* ws = (char*)d_ws;

  __hip_bfloat16* AreT = (__hip_bfloat16*)(ws + OFF_ARE);
  __hip_bfloat16* AtT = (__hip_bfloat16*)(ws + OFF_ATT);
  __hip_bfloat16* xb = (__hip_bfloat16*)(ws + OFF_XB);
  __hip_bfloat16* errb = (__hip_bfloat16*)(ws + OFF_ERR);
  float* yT = (float*)(ws + OFF_YT);
  int* bars = (int*)(ws + OFF_BAR);

  prep_fwd<<<256, 512, 0, stream>>>(A, AreT);
  prep_bwd<<<512, 256, 0, stream>>>(A, AtT);
  prep_y<<<512, 256, 0, stream>>>(y, yT);
  zero_flags<<<1, 256, 0, stream>>>(bars);

  ista_persist<<<256, 512, 0, stream>>>(AreT, AtT, yT, errb, xb, out, bars);
}